// Round 8
// baseline (334.824 us; speedup 1.0000x reference)
//
#include <hip/hip_runtime.h>
#include <hip/hip_bf16.h>
#include <hip/hip_cooperative_groups.h>

namespace cg = cooperative_groups;

#define DIM   1024
#define HEADS 16
#define B     2
#define N     2048
#define BLOCKS 1024   // cooperative grid: needs 4 blocks/CU on 256 CUs

typedef float f32x4 __attribute__((ext_vector_type(4)));

__device__ __forceinline__ float logsig(float z) {
  return fminf(z, 0.0f) - log1pf(__expf(-fabsf(z)));
}

// ---------------------------------------------------------------------------
// Fused: phase1 logits -> grid.sync -> phase2 cumsum -> grid.sync -> phase3.
// __launch_bounds__(256, 4): 4 waves/EU -> 16 waves/CU -> caps VGPR at 128 so
// 4 blocks/CU co-reside (1024 blocks co-resident, cooperative launch legal).
// ---------------------------------------------------------------------------
__global__ __launch_bounds__(256, 4) void fused_kernel(
    const float* __restrict__ x, const float* __restrict__ W,
    const float* __restrict__ bias, float* __restrict__ out,
    float* __restrict__ logits, float* __restrict__ fg) {
  cg::grid_group grid = cg::this_grid();
  const int tid  = threadIdx.x;
  const int wave = tid >> 6;
  const int lane = tid & 63;

  // ---- Phase 1: logits[b,h,n], 4 bn-rows per block, 4 heads per wave ----
  {
    const int bn0 = blockIdx.x * 4;
    for (int r = 0; r < 4; ++r) {
      const int bn = bn0 + r;
      const f32x4* xrow = (const f32x4*)(x + (size_t)bn * DIM);
      f32x4 xv[4];
#pragma unroll
      for (int k = 0; k < 4; ++k) xv[k] = xrow[lane * 4 + k];
#pragma unroll
      for (int hh = 0; hh < 4; ++hh) {
        const int h = wave * 4 + hh;
        const f32x4* wrow = (const f32x4*)(W + (size_t)h * DIM);
        float s = 0.0f;
#pragma unroll
        for (int k = 0; k < 4; ++k) {
          f32x4 wv = wrow[lane * 4 + k];
          s += wv.x * xv[k].x + wv.y * xv[k].y + wv.z * xv[k].z + wv.w * xv[k].w;
        }
#pragma unroll
        for (int off = 32; off > 0; off >>= 1) s += __shfl_down(s, off, 64);
        if (lane == 0) {
          const int b = bn >> 11;
          const int n = bn & (N - 1);
          logits[((size_t)(b * HEADS + h)) * N + n] = s + bias[h];
        }
      }
    }
  }

  grid.sync();

  // ---- Phase 2: fg[bh,:] = cumsum(logsig(logits[bh,:])), blocks 0..31 ----
  if (blockIdx.x < B * HEADS) {
    const int bh = blockIdx.x;
    const float* lp = logits + (size_t)bh * N;
    float*       fp = fg     + (size_t)bh * N;

    f32x4 a = ((const f32x4*)lp)[tid * 2];
    f32x4 c = ((const f32x4*)lp)[tid * 2 + 1];
    float v[8] = {a.x, a.y, a.z, a.w, c.x, c.y, c.z, c.w};

    float run = 0.0f;
#pragma unroll
    for (int i = 0; i < 8; ++i) { v[i] = logsig(v[i]); run += v[i]; v[i] = run; }
    const float total = run;

    float sc = total;
#pragma unroll
    for (int off = 1; off < 64; off <<= 1) {
      float t = __shfl_up(sc, off, 64);
      if (lane >= off) sc += t;
    }

    __shared__ float wtot[4];
    if (lane == 63) wtot[wave] = sc;
    __syncthreads();
    float wofs = 0.0f;
    for (int w = 0; w < wave; ++w) wofs += wtot[w];

    const float base = wofs + sc - total;
    f32x4 o0 = {base + v[0], base + v[1], base + v[2], base + v[3]};
    f32x4 o1 = {base + v[4], base + v[5], base + v[6], base + v[7]};
    ((f32x4*)fp)[tid * 2]     = o0;
    ((f32x4*)fp)[tid * 2 + 1] = o1;
  }

  grid.sync();

  // ---- Phase 3: out[bh,i,j] = fg[bh,i] - fg[bh,j], 16 rows per wave ----
  {
    const int row0 = (blockIdx.x * 4 + wave) * 16;   // 4096 waves * 16 rows
    const int bh   = row0 >> 11;
    const int i0   = row0 & (N - 1);
    const float* frow = fg + ((size_t)bh << 11);

    const f32x4* fj = (const f32x4*)frow;
    f32x4 vj[8];
#pragma unroll
    for (int k = 0; k < 8; ++k) vj[k] = fj[lane + k * 64];

    f32x4* orow = (f32x4*)(out + ((size_t)row0 << 11));
#pragma unroll 2
    for (int q = 0; q < 4; ++q) {
      f32x4 t = *(const f32x4*)(frow + i0 + 4 * q);
      const float fi[4] = {t.x, t.y, t.z, t.w};
#pragma unroll
      for (int r = 0; r < 4; ++r) {
        const float f = fi[r];
#pragma unroll
        for (int k = 0; k < 8; ++k) {
          f32x4 v = vj[k];
          f32x4 s = {f - v.x, f - v.y, f - v.z, f - v.w};
          orow[lane + k * 64] = s;
        }
        orow += N / 4;   // contiguous 128 KB stream per wave
      }
    }
  }
}

// ---------------------------------------------------------------------------
// Fallback path (round-4 kernels, proven 119.5 us) in case the cooperative
// launch is rejected (co-residency) — keeps correctness guaranteed.
// ---------------------------------------------------------------------------
__global__ __launch_bounds__(256) void logits_kernel(
    const float* __restrict__ x, const float* __restrict__ W,
    const float* __restrict__ bias, float* __restrict__ logits) {
  const int bn   = blockIdx.x;
  const int tid  = threadIdx.x;
  const int wave = tid >> 6;
  const int lane = tid & 63;

  const f32x4* xrow = (const f32x4*)(x + (size_t)bn * DIM);
  f32x4 xv[4];
#pragma unroll
  for (int k = 0; k < 4; ++k) xv[k] = xrow[lane * 4 + k];

#pragma unroll
  for (int hh = 0; hh < 4; ++hh) {
    const int h = wave * 4 + hh;
    const f32x4* wrow = (const f32x4*)(W + (size_t)h * DIM);
    float s = 0.0f;
#pragma unroll
    for (int k = 0; k < 4; ++k) {
      f32x4 wv = wrow[lane * 4 + k];
      s += wv.x * xv[k].x + wv.y * xv[k].y + wv.z * xv[k].z + wv.w * xv[k].w;
    }
#pragma unroll
    for (int off = 32; off > 0; off >>= 1) s += __shfl_down(s, off, 64);
    if (lane == 0) {
      const int b = bn >> 11;
      const int n = bn & (N - 1);
      logits[((size_t)(b * HEADS + h)) * N + n] = s + bias[h];
    }
  }
}

__global__ __launch_bounds__(256) void cumsum_kernel(
    const float* __restrict__ logits, float* __restrict__ fg) {
  const int bh  = blockIdx.x;
  const int tid = threadIdx.x;
  const float* lp = logits + (size_t)bh * N;
  float*       fp = fg     + (size_t)bh * N;

  f32x4 a = ((const f32x4*)lp)[tid * 2];
  f32x4 c = ((const f32x4*)lp)[tid * 2 + 1];
  float v[8] = {a.x, a.y, a.z, a.w, c.x, c.y, c.z, c.w};

  float run = 0.0f;
#pragma unroll
  for (int i = 0; i < 8; ++i) { v[i] = logsig(v[i]); run += v[i]; v[i] = run; }
  const float total = run;

  const int lane = tid & 63, wv = tid >> 6;
  float sc = total;
#pragma unroll
  for (int off = 1; off < 64; off <<= 1) {
    float t = __shfl_up(sc, off, 64);
    if (lane >= off) sc += t;
  }

  __shared__ float wtot[4];
  if (lane == 63) wtot[wv] = sc;
  __syncthreads();
  float wofs = 0.0f;
  for (int w = 0; w < wv; ++w) wofs += wtot[w];

  const float base = wofs + sc - total;
  f32x4 o0 = {base + v[0], base + v[1], base + v[2], base + v[3]};
  f32x4 o1 = {base + v[4], base + v[5], base + v[6], base + v[7]};
  ((f32x4*)fp)[tid * 2]     = o0;
  ((f32x4*)fp)[tid * 2 + 1] = o1;
}

__global__ __launch_bounds__(256) void outer_kernel(
    const float* __restrict__ fg, float* __restrict__ out) {
  const int row = blockIdx.x;
  const int bh  = row >> 11;
  const float fi = fg[(size_t)bh * N + (row & (N - 1))];
  const f32x4* fj = (const f32x4*)(fg + (size_t)bh * N);
  f32x4* o = (f32x4*)(out + (size_t)row * N);
  const int tid = threadIdx.x;

  f32x4 v0 = fj[tid];
  f32x4 v1 = fj[tid + 256];
  f32x4 r0 = {fi - v0.x, fi - v0.y, fi - v0.z, fi - v0.w};
  f32x4 r1 = {fi - v1.x, fi - v1.y, fi - v1.z, fi - v1.w};
  o[tid]       = r0;
  o[tid + 256] = r1;
}

extern "C" void kernel_launch(void* const* d_in, const int* in_sizes, int n_in,
                              void* d_out, int out_size, void* d_ws, size_t ws_size,
                              hipStream_t stream) {
  const float* x    = (const float*)d_in[0];   // [B, N, DIM]
  const float* W    = (const float*)d_in[1];   // [HEADS, DIM]
  const float* bias = (const float*)d_in[2];   // [HEADS]
  float* out = (float*)d_out;                  // [B, HEADS, N, N]

  float* logits = (float*)d_ws;                            // 256 KB
  float* fg     = logits + (size_t)B * HEADS * N;          // 256 KB

  void* args[] = {(void*)&x, (void*)&W, (void*)&bias,
                  (void*)&out, (void*)&logits, (void*)&fg};
  hipError_t err = hipLaunchCooperativeKernel((const void*)fused_kernel,
                                              dim3(BLOCKS), dim3(256), args, 0,
                                              stream);
  if (err != hipSuccess) {
    // cooperative launch rejected -> proven 3-kernel path
    logits_kernel<<<B * N, 256, 0, stream>>>(x, W, bias, logits);
    cumsum_kernel<<<B * HEADS, 256, 0, stream>>>(logits, fg);
    outer_kernel<<<B * HEADS * N, 256, 0, stream>>>(fg, out);
  }
}

// Round 9
// 129.421 us; speedup vs baseline: 2.5871x; 2.5871x over previous
//
#include <hip/hip_runtime.h>
#include <hip/hip_bf16.h>

#define DIM   1024
#define HEADS 16
#define B     2
#define N     2048

typedef float f32x4 __attribute__((ext_vector_type(4)));

__device__ __forceinline__ float logsig(float z) {
  return fminf(z, 0.0f) - log1pf(__expf(-fabsf(z)));
}

// ---------------------------------------------------------------------------
// Kernel 1: logits[b,h,n] = dot(x[b,n,:], W[h,:]) + bias[h]
// One block per (b,n). 256 threads = 4 waves; each wave computes 4 heads.
// ---------------------------------------------------------------------------
__global__ __launch_bounds__(256) void logits_kernel(
    const float* __restrict__ x, const float* __restrict__ W,
    const float* __restrict__ bias, float* __restrict__ logits) {
  const int bn   = blockIdx.x;
  const int tid  = threadIdx.x;
  const int wave = tid >> 6;
  const int lane = tid & 63;

  const f32x4* xrow = (const f32x4*)(x + (size_t)bn * DIM);
  f32x4 xv[4];
#pragma unroll
  for (int k = 0; k < 4; ++k) xv[k] = xrow[lane * 4 + k];

#pragma unroll
  for (int hh = 0; hh < 4; ++hh) {
    const int h = wave * 4 + hh;
    const f32x4* wrow = (const f32x4*)(W + (size_t)h * DIM);
    float s = 0.0f;
#pragma unroll
    for (int k = 0; k < 4; ++k) {
      f32x4 wv = wrow[lane * 4 + k];
      s += wv.x * xv[k].x + wv.y * xv[k].y + wv.z * xv[k].z + wv.w * xv[k].w;
    }
#pragma unroll
    for (int off = 32; off > 0; off >>= 1) s += __shfl_down(s, off, 64);
    if (lane == 0) {
      const int b = bn >> 11;
      const int n = bn & (N - 1);
      logits[((size_t)(b * HEADS + h)) * N + n] = s + bias[h];
    }
  }
}

// ---------------------------------------------------------------------------
// Kernel 2: fg[bh, :] = cumsum(logsigmoid(logits[bh, :]))
// One block per (b,h) = 32 blocks.
// ---------------------------------------------------------------------------
__global__ __launch_bounds__(256) void cumsum_kernel(
    const float* __restrict__ logits, float* __restrict__ fg) {
  const int bh  = blockIdx.x;
  const int tid = threadIdx.x;
  const float* lp = logits + (size_t)bh * N;
  float*       fp = fg     + (size_t)bh * N;

  f32x4 a = ((const f32x4*)lp)[tid * 2];
  f32x4 c = ((const f32x4*)lp)[tid * 2 + 1];
  float v[8] = {a.x, a.y, a.z, a.w, c.x, c.y, c.z, c.w};

  float run = 0.0f;
#pragma unroll
  for (int i = 0; i < 8; ++i) { v[i] = logsig(v[i]); run += v[i]; v[i] = run; }
  const float total = run;

  const int lane = tid & 63, wv = tid >> 6;
  float sc = total;
#pragma unroll
  for (int off = 1; off < 64; off <<= 1) {
    float t = __shfl_up(sc, off, 64);
    if (lane >= off) sc += t;
  }

  __shared__ float wtot[4];
  if (lane == 63) wtot[wv] = sc;
  __syncthreads();
  float wofs = 0.0f;
  for (int w = 0; w < wv; ++w) wofs += wtot[w];

  const float base = wofs + sc - total;
  f32x4 o0 = {base + v[0], base + v[1], base + v[2], base + v[3]};
  f32x4 o1 = {base + v[4], base + v[5], base + v[6], base + v[7]};
  ((f32x4*)fp)[tid * 2]     = o0;
  ((f32x4*)fp)[tid * 2 + 1] = o1;
}

// ---------------------------------------------------------------------------
// Kernel 3: out[bh,i,j] = fg[bh,i] - fg[bh,j].
// FEW WAVES x LONG STREAMS (fill-kernel regime): 256 blocks (1/CU) x 4 waves;
// each wave owns 64 consecutive rows of one (b,h) = one contiguous 512 KB
// store stream. fj row (vj[8]) and all 64 fi scalars preloaded to registers;
// steady state is 512 back-to-back dwordx4 stores, zero loads.
// ---------------------------------------------------------------------------
__global__ __launch_bounds__(256) void outer_kernel(
    const float* __restrict__ fg, float* __restrict__ out) {
  const int tid  = threadIdx.x;
  const int wave = tid >> 6;
  const int lane = tid & 63;
  const int gw   = blockIdx.x * 4 + wave;   // 0..1023
  const int row0 = gw * 64;                 // 64 consecutive rows per wave
  const int bh   = row0 >> 11;              // 32 waves per bh, same bh all 64
  const int i0   = row0 & (N - 1);

  const float* frow = fg + ((size_t)bh << 11);

  // full fj row in registers
  const f32x4* fj = (const f32x4*)frow;
  f32x4 vj[8];
#pragma unroll
  for (int k = 0; k < 8; ++k) vj[k] = fj[lane + k * 64];

  // all 64 fi scalars in registers (uniform loads)
  f32x4 fi4[16];
#pragma unroll
  for (int q = 0; q < 16; ++q) fi4[q] = *(const f32x4*)(frow + i0 + 4 * q);

  f32x4* orow = (f32x4*)(out + ((size_t)row0 << 11));
#pragma unroll
  for (int q = 0; q < 16; ++q) {
    const float fi[4] = {fi4[q].x, fi4[q].y, fi4[q].z, fi4[q].w};
#pragma unroll
    for (int r = 0; r < 4; ++r) {
      const float f = fi[r];
#pragma unroll
      for (int k = 0; k < 8; ++k) {
        f32x4 v = vj[k];
        f32x4 s = {f - v.x, f - v.y, f - v.z, f - v.w};
        orow[lane + k * 64] = s;
      }
      orow += N / 4;   // next row: stream stays contiguous
    }
  }
}

extern "C" void kernel_launch(void* const* d_in, const int* in_sizes, int n_in,
                              void* d_out, int out_size, void* d_ws, size_t ws_size,
                              hipStream_t stream) {
  const float* x    = (const float*)d_in[0];   // [B, N, DIM]
  const float* W    = (const float*)d_in[1];   // [HEADS, DIM]
  const float* bias = (const float*)d_in[2];   // [HEADS]
  float* out = (float*)d_out;                  // [B, HEADS, N, N]

  float* logits = (float*)d_ws;                            // 256 KB
  float* fg     = logits + (size_t)B * HEADS * N;          // 256 KB

  logits_kernel<<<B * N, 256, 0, stream>>>(x, W, bias, logits);
  cumsum_kernel<<<B * HEADS, 256, 0, stream>>>(logits, fg);
  outer_kernel<<<256, 256, 0, stream>>>(fg, out);
}

// Round 10
// 119.216 us; speedup vs baseline: 2.8086x; 1.0856x over previous
//
#include <hip/hip_runtime.h>
#include <hip/hip_bf16.h>

#define DIM   1024
#define HEADS 16
#define B     2
#define N     2048
#define ROWS_PER_BLK 32   // fused outer: 32 output rows per block

typedef float f32x4 __attribute__((ext_vector_type(4)));

__device__ __forceinline__ float logsig(float z) {
  return fminf(z, 0.0f) - log1pf(__expf(-fabsf(z)));
}

// ---------------------------------------------------------------------------
// Kernel 1: logits[b,h,n] = dot(x[b,n,:], W[h,:]) + bias[h]
// One block per (b,n). 256 threads = 4 waves; each wave computes 4 heads.
// ---------------------------------------------------------------------------
__global__ __launch_bounds__(256) void logits_kernel(
    const float* __restrict__ x, const float* __restrict__ W,
    const float* __restrict__ bias, float* __restrict__ logits) {
  const int bn   = blockIdx.x;
  const int tid  = threadIdx.x;
  const int wave = tid >> 6;
  const int lane = tid & 63;

  const f32x4* xrow = (const f32x4*)(x + (size_t)bn * DIM);
  f32x4 xv[4];
#pragma unroll
  for (int k = 0; k < 4; ++k) xv[k] = xrow[lane * 4 + k];

#pragma unroll
  for (int hh = 0; hh < 4; ++hh) {
    const int h = wave * 4 + hh;
    const f32x4* wrow = (const f32x4*)(W + (size_t)h * DIM);
    float s = 0.0f;
#pragma unroll
    for (int k = 0; k < 4; ++k) {
      f32x4 wv = wrow[lane * 4 + k];
      s += wv.x * xv[k].x + wv.y * xv[k].y + wv.z * xv[k].z + wv.w * xv[k].w;
    }
#pragma unroll
    for (int off = 32; off > 0; off >>= 1) s += __shfl_down(s, off, 64);
    if (lane == 0) {
      const int b = bn >> 11;
      const int n = bn & (N - 1);
      logits[((size_t)(b * HEADS + h)) * N + n] = s + bias[h];
    }
  }
}

// ---------------------------------------------------------------------------
// Kernel 2 (fused cumsum + outer): each block recomputes its bh's fg row
// (logsigmoid + block-wide scan, into LDS), then writes 32 output rows with
// the proven r4 pattern: all 4 waves jointly write one 8 KB row, rows
// consecutive -> 256 KB contiguous stream per block. 2048 blocks, 8/CU.
// ---------------------------------------------------------------------------
__global__ __launch_bounds__(256) void fused_outer_kernel(
    const float* __restrict__ logits, float* __restrict__ out) {
  const int blk  = blockIdx.x;        // 0..2047
  const int bh   = blk >> 6;          // 64 blocks per bh
  const int i0   = (blk & 63) * ROWS_PER_BLK;
  const int tid  = threadIdx.x;
  const int lane = tid & 63;
  const int wave = tid >> 6;

  __shared__ float fgrow[N];          // 8 KB: the cumsum row for this bh
  __shared__ float wtot[4];

  // ---- prologue: fg row = cumsum(logsig(logits[bh,:])) (same math as r4 k2)
  {
    const float* lp = logits + (size_t)bh * N;
    f32x4 a = ((const f32x4*)lp)[tid * 2];
    f32x4 c = ((const f32x4*)lp)[tid * 2 + 1];
    float v[8] = {a.x, a.y, a.z, a.w, c.x, c.y, c.z, c.w};

    float run = 0.0f;
#pragma unroll
    for (int i = 0; i < 8; ++i) { v[i] = logsig(v[i]); run += v[i]; v[i] = run; }
    const float total = run;

    float sc = total;
#pragma unroll
    for (int off = 1; off < 64; off <<= 1) {
      float t = __shfl_up(sc, off, 64);
      if (lane >= off) sc += t;
    }
    if (lane == 63) wtot[wave] = sc;
    __syncthreads();
    float wofs = 0.0f;
    for (int w = 0; w < wave; ++w) wofs += wtot[w];

    const float base = wofs + sc - total;   // exclusive prefix for this thread
    f32x4 o0 = {base + v[0], base + v[1], base + v[2], base + v[3]};
    f32x4 o1 = {base + v[4], base + v[5], base + v[6], base + v[7]};
    ((f32x4*)fgrow)[tid * 2]     = o0;
    ((f32x4*)fgrow)[tid * 2 + 1] = o1;
  }
  __syncthreads();

  // ---- epilogue: 32 rows, r4 store pattern (block writes each row jointly)
  // thread's fixed slice of the fj row, held in registers
  const f32x4 v0 = ((const f32x4*)fgrow)[tid];
  const f32x4 v1 = ((const f32x4*)fgrow)[tid + 256];

  f32x4* orow = (f32x4*)(out + ((size_t)(bh * N + i0)) * N);
#pragma unroll 4
  for (int r = 0; r < ROWS_PER_BLK; ++r) {
    const float f = fgrow[i0 + r];    // LDS broadcast
    f32x4 r0 = {f - v0.x, f - v0.y, f - v0.z, f - v0.w};
    f32x4 r1 = {f - v1.x, f - v1.y, f - v1.z, f - v1.w};
    orow[tid]       = r0;
    orow[tid + 256] = r1;
    orow += N / 4;                    // next consecutive row
  }
}

extern "C" void kernel_launch(void* const* d_in, const int* in_sizes, int n_in,
                              void* d_out, int out_size, void* d_ws, size_t ws_size,
                              hipStream_t stream) {
  const float* x    = (const float*)d_in[0];   // [B, N, DIM]
  const float* W    = (const float*)d_in[1];   // [HEADS, DIM]
  const float* bias = (const float*)d_in[2];   // [HEADS]
  float* out = (float*)d_out;                  // [B, HEADS, N, N]

  float* logits = (float*)d_ws;                // 256 KB scratch

  logits_kernel<<<B * N, 256, 0, stream>>>(x, W, bias, logits);
  fused_outer_kernel<<<B * HEADS * (N / ROWS_PER_BLK), 256, 0, stream>>>(logits, out);
}